// Round 15
// baseline (226.730 us; speedup 1.0000x reference)
//
#include <hip/hip_runtime.h>

#define NG 72

typedef float floatx2 __attribute__((ext_vector_type(2)));

// packed fp32 FMA: acc.{x,y} += win.{word} * wgt.{x,y}
// win: one 32-bit word of the float2 pair broadcast to BOTH halves via op_sel.
// wgt: SGPR pair {w_ocA, w_ocB} (VOP3P allows one scalar source).
#define PKFMA(acc_, win_, wgt_, odd_)                                            \
  do {                                                                           \
    if (odd_) asm("v_pk_fma_f32 %0, %1, %2, %0 op_sel:[1,0,0] op_sel_hi:[1,1,1]" \
                  : "+v"(acc_) : "v"(win_), "s"(wgt_));                          \
    else      asm("v_pk_fma_f32 %0, %1, %2, %0 op_sel:[0,0,0] op_sel_hi:[0,1,1]" \
                  : "+v"(acc_) : "v"(win_), "s"(wgt_));                          \
  } while (0)

// ---------------- prep: pack weight oc-pairs (oc, oc+half) as float2 --------
// wf layout (float2 units): conv1 [g][ocp<4][ic<3][t<25] @0 (21600)
//   conv2 [g][ocp<8][ic<8][t<9] @21600 (41472)
//   conv3 [g][ocg<4][o8p<4][ic<16][t<9] @63072 (165888). total 228960 float2.
__global__ __launch_bounds__(256) void prep_k(const float* __restrict__ w1,
                                              const float* __restrict__ w2,
                                              const float* __restrict__ w3,
                                              floatx2* __restrict__ wf) {
  const int i = blockIdx.x * 256 + threadIdx.x;
  if (i < 21600) {
    const int t = i % 25; int r = i / 25;
    const int ic = r % 3; r /= 3;
    const int ocp = r % 4; const int g = r / 4;
    const float* base = w1 + (size_t)((g * 8 + ocp) * 3 + ic) * 25 + t;
    wf[i] = (floatx2){base[0], base[4 * 75]};          // (oc, oc+4)
  } else if (i < 63072) {
    const int j = i - 21600;
    const int t = j % 9; int r = j / 9;
    const int ic = r % 8; r /= 8;
    const int ocp = r % 8; const int g = r / 8;
    const float* base = w2 + (size_t)((g * 16 + ocp) * 8 + ic) * 9 + t;
    wf[i] = (floatx2){base[0], base[8 * 72]};          // (oc, oc+8)
  } else if (i < 228960) {
    const int j = i - 63072;
    const int t = j % 9; int r = j / 9;
    const int ic = r % 16; r /= 16;
    const int o8p = r % 4; r /= 4;
    const int ocg = r % 4; const int g = r / 4;
    const float* base = w3 + (size_t)((g * 32 + ocg * 8 + o8p) * 16 + ic) * 9 + t;
    wf[i] = (floatx2){base[0], base[4 * 144]};         // (o8p, o8p+4) within wave's 8
  }
}

// ---------------- conv1: (64,216,46,46) -> k5 g72 (3->8) -> relu -> pool2 ----
// 448-thread block per (b,g). fp32 pk_fma over oc-pairs (oc, oc+4); window
// rows as aligned float2 (ix even); weights SGPR pairs.
__global__ __launch_bounds__(448) void conv1_k(const float* __restrict__ x,
                                               const floatx2* __restrict__ wf,
                                               const float* __restrict__ bias,
                                               float* __restrict__ out) {
  const int b = blockIdx.x / NG, g = blockIdx.x % NG;
  __shared__ float sx[3][46][48];   // pitch 48 f32: even cols 8B-aligned
  const float* xp = x + (size_t)(b * 216 + g * 3) * 2116;
  const float4* q4 = (const float4*)xp;   // 3*2116 = 1587 float4, exact
  for (int i = threadIdx.x; i < 1587; i += 448) {
    const float4 v = q4[i];
#pragma unroll
    for (int j = 0; j < 4; j++) {
      const int k = 4 * i + j;
      const int ic = k / 2116, rem = k % 2116;
      sx[ic][rem / 46][rem % 46] = (&v.x)[j];
    }
  }
  __syncthreads();
  const unsigned long long* wu = (const unsigned long long*)wf;  // pairs, uniform
  const float* bg = bias + g * 8;                                // uniform
  const int tid = threadIdx.x;
  if (tid < 441) {
    const int yl = tid / 21, px = tid % 21;
    const int iy = 2 * yl, ix = 2 * px;
    floatx2 acc[4][4];
#pragma unroll
    for (int o = 0; o < 4; o++)
#pragma unroll
      for (int q = 0; q < 4; q++) acc[o][q] = (floatx2){0.f, 0.f};
#pragma unroll 1   // per-ic phases: window live range = 36 VGPR
    for (int ic = 0; ic < 3; ic++) {
      floatx2 wr[6][3];   // rows iy..iy+5, col pairs {0,1}{2,3}{4,5}
#pragma unroll
      for (int r = 0; r < 6; r++)
#pragma unroll
        for (int j2 = 0; j2 < 3; j2++)
          wr[r][j2] = *(const floatx2*)&sx[ic][iy + r][ix + 2 * j2];
#pragma unroll
      for (int ocp = 0; ocp < 4; ocp++) {
        const unsigned long long* wq = wu + ((size_t)(g * 4 + ocp) * 3 + ic) * 25;
#pragma unroll
        for (int ky = 0; ky < 5; ky++)
#pragma unroll
          for (int kx = 0; kx < 5; kx++) {
            const unsigned long long wv = wq[ky * 5 + kx];   // uniform -> SGPR pair
            PKFMA(acc[ocp][0], wr[ky][kx >> 1],           wv, kx & 1);
            PKFMA(acc[ocp][1], wr[ky][(kx + 1) >> 1],     wv, (kx + 1) & 1);
            PKFMA(acc[ocp][2], wr[ky + 1][kx >> 1],       wv, kx & 1);
            PKFMA(acc[ocp][3], wr[ky + 1][(kx + 1) >> 1], wv, (kx + 1) & 1);
          }
      }
    }
#pragma unroll
    for (int ocp = 0; ocp < 4; ocp++) {
      const float vx = fmaxf(fmaxf(acc[ocp][0].x, acc[ocp][1].x),
                             fmaxf(acc[ocp][2].x, acc[ocp][3].x)) + bg[ocp];
      const float vy = fmaxf(fmaxf(acc[ocp][0].y, acc[ocp][1].y),
                             fmaxf(acc[ocp][2].y, acc[ocp][3].y)) + bg[ocp + 4];
      out[(size_t)(b * 576 + g * 8 + ocp) * 441 + yl * 21 + px]       = fmaxf(vx, 0.f);
      out[(size_t)(b * 576 + g * 8 + ocp + 4) * 441 + yl * 21 + px]   = fmaxf(vy, 0.f);
    }
  }
}

// ---------------- conv2: (64,576,21,21) -> k3 (8->16) -> relu -> pool2 ------
#define C2_NBB 3
__global__ __launch_bounds__(256) void conv2_k(const float* __restrict__ x,
                                               const floatx2* __restrict__ wf,
                                               const float* __restrict__ bias,
                                               float* __restrict__ out) {
  const int g = blockIdx.x % NG, b0 = (blockIdx.x / NG) * C2_NBB;
  const int nbb = min(C2_NBB, 64 - b0);
  __shared__ float sx[C2_NBB][8][21][22];   // pitch 22: even cols 8B-aligned
  for (int bb = 0; bb < nbb; bb++) {
    const float* xp = x + (size_t)((b0 + bb) * 576 + g * 8) * 441;
    for (int i = threadIdx.x; i < 8 * 441; i += 256) {
      const int ic = i / 441, rem = i % 441;
      sx[bb][ic][rem / 21][rem % 21] = xp[i];
    }
  }
  __syncthreads();
  const unsigned long long* wu = (const unsigned long long*)wf;  // uniform
  const float* bg = bias + g * 16;                               // uniform
  for (int u = threadIdx.x; u < nbb * 81; u += 256) {
    const int bb = u / 81, pp = u % 81, py = pp / 9, px = pp % 9;
    const int iy = 2 * py, ix = 2 * px;
    floatx2 acc[8][4];
#pragma unroll
    for (int o = 0; o < 8; o++)
#pragma unroll
      for (int q = 0; q < 4; q++) acc[o][q] = (floatx2){0.f, 0.f};
#pragma unroll 1
    for (int ic = 0; ic < 8; ic++) {
      floatx2 wr[4][2];   // rows iy..iy+3, col pairs {0,1}{2,3}
#pragma unroll
      for (int r = 0; r < 4; r++)
#pragma unroll
        for (int j2 = 0; j2 < 2; j2++)
          wr[r][j2] = *(const floatx2*)&sx[bb][ic][iy + r][ix + 2 * j2];
#pragma unroll
      for (int ocp = 0; ocp < 8; ocp++) {
        const unsigned long long* wq = wu + ((size_t)(g * 8 + ocp) * 8 + ic) * 9;
#pragma unroll
        for (int ky = 0; ky < 3; ky++)
#pragma unroll
          for (int kx = 0; kx < 3; kx++) {
            const unsigned long long wv = wq[ky * 3 + kx];   // uniform -> SGPR pair
            PKFMA(acc[ocp][0], wr[ky][kx >> 1],           wv, kx & 1);
            PKFMA(acc[ocp][1], wr[ky][(kx + 1) >> 1],     wv, (kx + 1) & 1);
            PKFMA(acc[ocp][2], wr[ky + 1][kx >> 1],       wv, kx & 1);
            PKFMA(acc[ocp][3], wr[ky + 1][(kx + 1) >> 1], wv, (kx + 1) & 1);
          }
      }
    }
#pragma unroll
    for (int ocp = 0; ocp < 8; ocp++) {
      const float vx = fmaxf(fmaxf(acc[ocp][0].x, acc[ocp][1].x),
                             fmaxf(acc[ocp][2].x, acc[ocp][3].x)) + bg[ocp];
      const float vy = fmaxf(fmaxf(acc[ocp][0].y, acc[ocp][1].y),
                             fmaxf(acc[ocp][2].y, acc[ocp][3].y)) + bg[ocp + 8];
      out[(size_t)((b0 + bb) * 1152 + g * 16 + ocp) * 81 + pp]     = fmaxf(vx, 0.f);
      out[(size_t)((b0 + bb) * 1152 + g * 16 + ocp + 8) * 81 + pp] = fmaxf(vy, 0.f);
    }
  }
}

// ---------------- conv3: (64,1152,9,9) -> k3 (16->32) -> relu -> pool2 ------
#define C3_NBB 7
__global__ __launch_bounds__(256) void conv3_k(const float* __restrict__ x,
                                               const floatx2* __restrict__ wf,
                                               const float* __restrict__ bias,
                                               float* __restrict__ out) {
  const int g = blockIdx.x % NG, b0 = (blockIdx.x / NG) * C3_NBB;
  const int nbb = min(C3_NBB, 64 - b0);
  __shared__ float sx[C3_NBB][16 * 90 + 2];   // per-ic [9][10]: even cols aligned
  for (int bb = 0; bb < nbb; bb++) {
    const float* xp = x + (size_t)((b0 + bb) * 1152 + g * 16) * 81;
    for (int i = threadIdx.x; i < 16 * 81; i += 256) {
      const int ic = i / 81, rem = i % 81;
      sx[bb][ic * 90 + (rem / 9) * 10 + rem % 9] = xp[i];
    }
  }
  __syncthreads();
  const int ocg = __builtin_amdgcn_readfirstlane(threadIdx.x >> 6);  // uniform
  const unsigned long long* wu = (const unsigned long long*)wf
                               + (size_t)(g * 4 + ocg) * 4 * 16 * 9;  // uniform
  const float* bg = bias + g * 32 + ocg * 8;                          // uniform
  const int lane = threadIdx.x & 63;
  const int bb = lane / 9, pp = lane % 9;
  if (bb < nbb) {
    const int py = pp / 3, px = pp % 3, iy = 2 * py, ix = 2 * px;
    const float* sxb = &sx[bb][0];
    floatx2 acc[4][4];
#pragma unroll
    for (int o = 0; o < 4; o++)
#pragma unroll
      for (int q = 0; q < 4; q++) acc[o][q] = (floatx2){0.f, 0.f};
#pragma unroll 1
    for (int ic = 0; ic < 16; ic++) {
      floatx2 wr[4][2];
#pragma unroll
      for (int r = 0; r < 4; r++)
#pragma unroll
        for (int j2 = 0; j2 < 2; j2++)
          wr[r][j2] = *(const floatx2*)&sxb[ic * 90 + (iy + r) * 10 + ix + 2 * j2];
#pragma unroll
      for (int o8p = 0; o8p < 4; o8p++) {
        const unsigned long long* wq = wu + ((size_t)o8p * 16 + ic) * 9;
#pragma unroll
        for (int ky = 0; ky < 3; ky++)
#pragma unroll
          for (int kx = 0; kx < 3; kx++) {
            const unsigned long long wv = wq[ky * 3 + kx];   // uniform -> SGPR pair
            PKFMA(acc[o8p][0], wr[ky][kx >> 1],           wv, kx & 1);
            PKFMA(acc[o8p][1], wr[ky][(kx + 1) >> 1],     wv, (kx + 1) & 1);
            PKFMA(acc[o8p][2], wr[ky + 1][kx >> 1],       wv, kx & 1);
            PKFMA(acc[o8p][3], wr[ky + 1][(kx + 1) >> 1], wv, (kx + 1) & 1);
          }
      }
    }
#pragma unroll
    for (int o8p = 0; o8p < 4; o8p++) {
      const float vx = fmaxf(fmaxf(acc[o8p][0].x, acc[o8p][1].x),
                             fmaxf(acc[o8p][2].x, acc[o8p][3].x)) + bg[o8p];
      const float vy = fmaxf(fmaxf(acc[o8p][0].y, acc[o8p][1].y),
                             fmaxf(acc[o8p][2].y, acc[o8p][3].y)) + bg[o8p + 4];
      out[(size_t)((b0 + bb) * 2304 + g * 32 + ocg * 8 + o8p) * 9 + pp]     = fmaxf(vx, 0.f);
      out[(size_t)((b0 + bb) * 2304 + g * 32 + ocg * 8 + o8p + 4) * 9 + pp] = fmaxf(vy, 0.f);
    }
  }
}

// ---------------- fused block-diagonal linear1 (288->64) + linear2 (64->2) + bias
__global__ __launch_bounds__(256) void lin_k(const float* __restrict__ h,
                                             const float* __restrict__ w1,
                                             const float* __restrict__ w2,
                                             const float* __restrict__ b2,
                                             float* __restrict__ out) {
  const int g = blockIdx.x % NG, b0 = (blockIdx.x / NG) * 32;
  __shared__ float sw1[64 * 292];
  __shared__ float sf[32 * 300];
  __shared__ float so[32 * 65];
  __shared__ float sw2[2 * 64];
  __shared__ float sb2[2];
  for (int i = threadIdx.x; i < 64 * 288; i += 256) {
    const int o = i / 288, k = i % 288;
    sw1[o * 292 + k] = w1[(size_t)(g * 64 + o) * 20736 + g * 288 + k];
  }
  for (int i = threadIdx.x; i < 32 * 288; i += 256) {
    const int bb = i / 288, k = i % 288;
    sf[bb * 300 + k] = h[(size_t)(b0 + bb) * 20736 + g * 288 + k];
  }
  if (threadIdx.x < 128) {
    const int j = threadIdx.x >> 6, o = threadIdx.x & 63;
    sw2[j * 64 + o] = w2[(size_t)(g * 2 + j) * 4608 + g * 64 + o];
  }
  if (threadIdx.x < 2) sb2[threadIdx.x] = b2[g * 2 + threadIdx.x];
  __syncthreads();
  const int bp = threadIdx.x & 15, oq = threadIdx.x >> 4;
  const int o0 = 4 * oq;
  float acc[2][4];
#pragma unroll
  for (int i = 0; i < 2; i++)
#pragma unroll
    for (int j = 0; j < 4; j++) acc[i][j] = 0.f;
  for (int k4 = 0; k4 < 72; k4++) {
    const float4 f0 = *(const float4*)&sf[bp * 300 + 4 * k4];
    const float4 f1 = *(const float4*)&sf[(bp + 16) * 300 + 4 * k4];
#pragma unroll
    for (int j = 0; j < 4; j++) {
      const float4 wr = *(const float4*)&sw1[(o0 + j) * 292 + 4 * k4];
      acc[0][j] = fmaf(f0.x, wr.x, fmaf(f0.y, wr.y, fmaf(f0.z, wr.z, fmaf(f0.w, wr.w, acc[0][j]))));
      acc[1][j] = fmaf(f1.x, wr.x, fmaf(f1.y, wr.y, fmaf(f1.z, wr.z, fmaf(f1.w, wr.w, acc[1][j]))));
    }
  }
#pragma unroll
  for (int j = 0; j < 4; j++) {
    so[bp * 65 + o0 + j] = acc[0][j];
    so[(bp + 16) * 65 + o0 + j] = acc[1][j];
  }
  __syncthreads();
  if (threadIdx.x < 64) {
    const int bb = threadIdx.x >> 1, j = threadIdx.x & 1;
    float a = sb2[j];
#pragma unroll 8
    for (int o = 0; o < 64; o++) a = fmaf(so[bb * 65 + o], sw2[j * 64 + o], a);
    out[(b0 + bb) * 144 + g * 2 + j] = a;
  }
}

extern "C" void kernel_launch(void* const* d_in, const int* in_sizes, int n_in,
                              void* d_out, int out_size, void* d_ws, size_t ws_size,
                              hipStream_t stream) {
  const float* x   = (const float*)d_in[0];
  const float* w1  = (const float*)d_in[1];
  const float* b1  = (const float*)d_in[2];
  const float* w2  = (const float*)d_in[3];
  const float* b2  = (const float*)d_in[4];
  const float* w3  = (const float*)d_in[5];
  const float* b3  = (const float*)d_in[6];
  const float* l1w = (const float*)d_in[7];
  const float* l2w = (const float*)d_in[8];
  const float* l2b = (const float*)d_in[9];
  float* out = (float*)d_out;

  float* h1 = (float*)d_ws;          // 64*576*21*21
  float* h2 = h1 + 16257024;         // 64*1152*9*9
  float* h3 = h2 + 5971968;          // 64*2304*3*3
  floatx2* wf = (floatx2*)(h3 + 1327104);   // packed fp32 weight pairs (228960 float2)

  prep_k <<<dim3(895),     256, 0, stream>>>(w1, w2, w3, wf);
  conv1_k<<<dim3(64 * NG), 448, 0, stream>>>(x,  wf,         b1, h1);
  conv2_k<<<dim3(22 * NG), 256, 0, stream>>>(h1, wf + 21600, b2, h2);
  conv3_k<<<dim3(10 * NG), 256, 0, stream>>>(h2, wf + 63072, b3, h3);
  lin_k  <<<dim3(2 * NG),  256, 0, stream>>>(h3, l1w, l2w, l2b, out);
}

// Round 16
// 202.918 us; speedup vs baseline: 1.1173x; 1.1173x over previous
//
#include <hip/hip_runtime.h>

#define NG 72

typedef _Float16 half2f __attribute__((ext_vector_type(2)));

__device__ __forceinline__ unsigned pkrtz(float a, float b) {
  return __builtin_bit_cast(unsigned, __builtin_amdgcn_cvt_pkrtz(a, b));
}
__device__ __forceinline__ float dot2(unsigned win, unsigned wgt, float acc) {
  return __builtin_amdgcn_fdot2(__builtin_bit_cast(half2f, win),
                                __builtin_bit_cast(half2f, wgt), acc, false);
}

// WIN: window element col c from de-interleaved even/odd register arrays
#define WIN(E, O, r, c) (((c) & 1) ? (O)[(r)][(c) >> 1] : (E)[(r)][(c) >> 1])

// h1 plane stride 444 (441 padded, %4==0), h2 plane stride 84 (81 padded).
#define H1S 444
#define H2S 84

// ---------------- prep: pack conv weights as half2 (ic-pairs) into d_ws ----
__global__ __launch_bounds__(256) void prep_k(const float* __restrict__ w1,
                                              const float* __restrict__ w2,
                                              const float* __restrict__ w3,
                                              unsigned* __restrict__ wf) {
  const int i = blockIdx.x * 256 + threadIdx.x;
  if (i < 28800) {
    const int t = i % 25, p = (i / 25) & 1, ocg = i / 50;
    const float* base = w1 + (size_t)ocg * 75 + t;
    const float a = base[p * 50];
    const float b = (p == 0) ? base[25] : 0.f;
    wf[i] = pkrtz(a, b);
  } else if (i < 70272) {
    const int j = i - 28800;
    const int t = j % 9, p = (j / 9) & 3, ocg = j / 36;
    const float* base = w2 + (size_t)ocg * 72 + t;
    wf[i] = pkrtz(base[2 * p * 9], base[(2 * p + 1) * 9]);
  } else if (i < 236160) {
    const int j = i - 70272;
    const int t = j % 9, p = (j / 9) & 7, ocg = j / 72;
    const float* base = w3 + (size_t)ocg * 144 + t;
    wf[i] = pkrtz(base[2 * p * 9], base[(2 * p + 1) * 9]);
  }
}

// ---------------- conv1: (64,216,46,46) -> k5 g72 (3->8) -> relu -> pool2 ----
// 448-thread block per (b,g). f16 ic-pair dot2, SGPR weights, even/odd layout.
// Output plane stride H1S=444 so conv2 can stage with float4.
__global__ __launch_bounds__(448) void conv1_k(const float* __restrict__ x,
                                               const unsigned* __restrict__ wf,
                                               const float* __restrict__ bias,
                                               float* __restrict__ out) {
  const int b = blockIdx.x / NG, g = blockIdx.x % NG;
  __shared__ unsigned sxe[2][46][26];   // even cols (23 used)
  __shared__ unsigned sxo[2][46][26];   // odd cols (23 used)
  const float* xp = x + (size_t)(b * 216 + g * 3) * 2116;
  const float4* q0 = (const float4*)xp;            // 529 float4 per plane, exact
  const float4* q1 = (const float4*)(xp + 2116);
  const float4* q2 = (const float4*)(xp + 2 * 2116);
  for (int i = threadIdx.x; i < 529; i += 448) {
    const float4 a = q0[i], c1 = q1[i], c2 = q2[i];
#pragma unroll
    for (int j = 0; j < 4; j++) {
      const int k = 4 * i + j, r = k / 46, cc = k % 46;
      const unsigned v0 = pkrtz((&a.x)[j], (&c1.x)[j]);
      const unsigned v1 = pkrtz((&c2.x)[j], 0.f);
      if (cc & 1) { sxo[0][r][cc >> 1] = v0; sxo[1][r][cc >> 1] = v1; }
      else        { sxe[0][r][cc >> 1] = v0; sxe[1][r][cc >> 1] = v1; }
    }
  }
  __syncthreads();
  const unsigned* wgq = wf + (size_t)(g * 8) * 50;   // [oc][p][25], uniform
  const float* bg = bias + g * 8;                    // uniform
  const int tid = threadIdx.x;
  if (tid < 441) {
    const int yl = tid / 21, px = tid % 21;
    const int iy = 2 * yl;
    float acc[8][4];
#pragma unroll
    for (int o = 0; o < 8; o++)
#pragma unroll
      for (int q = 0; q < 4; q++) acc[o][q] = 0.f;
#pragma unroll 1   // sequential ic-pair phases: keep window live range small
    for (int p = 0; p < 2; p++) {
      unsigned we[6][3], wo[6][3];
#pragma unroll
      for (int r = 0; r < 6; r++)
#pragma unroll
        for (int j = 0; j < 3; j++) {
          we[r][j] = sxe[p][iy + r][px + j];
          wo[r][j] = sxo[p][iy + r][px + j];
        }
#pragma unroll
      for (int oc = 0; oc < 8; oc++) {
        const unsigned* wq = wgq + (oc * 2 + p) * 25;   // uniform -> SGPR
#pragma unroll
        for (int ky = 0; ky < 5; ky++)
#pragma unroll
          for (int kx = 0; kx < 5; kx++) {
            const unsigned wv = wq[ky * 5 + kx];
            acc[oc][0] = dot2(WIN(we, wo, ky,     kx),     wv, acc[oc][0]);
            acc[oc][1] = dot2(WIN(we, wo, ky,     kx + 1), wv, acc[oc][1]);
            acc[oc][2] = dot2(WIN(we, wo, ky + 1, kx),     wv, acc[oc][2]);
            acc[oc][3] = dot2(WIN(we, wo, ky + 1, kx + 1), wv, acc[oc][3]);
          }
      }
    }
#pragma unroll
    for (int oc = 0; oc < 8; oc++) {
      const float v = fmaxf(fmaxf(acc[oc][0], acc[oc][1]), fmaxf(acc[oc][2], acc[oc][3])) + bg[oc];
      out[(size_t)(b * 576 + g * 8 + oc) * H1S + yl * 21 + px] = fmaxf(v, 0.f);
    }
  }
}

// ---------------- conv2: h1(stride 444) -> k3 (8->16) -> relu -> pool2 -> h2(84)
#define C2_NBB 3
__global__ __launch_bounds__(256) void conv2_k(const float* __restrict__ x,
                                               const unsigned* __restrict__ wf,
                                               const float* __restrict__ bias,
                                               float* __restrict__ out) {
  const int g = blockIdx.x % NG, b0 = (blockIdx.x / NG) * C2_NBB;
  const int nbb = min(C2_NBB, 64 - b0);
  __shared__ unsigned sxp[C2_NBB][4][21][22];   // half2 ic-pairs
  for (int bb = 0; bb < nbb; bb++) {
    const float* xp = x + (size_t)((b0 + bb) * 576 + g * 8) * H1S;
    // float4 staging: 4 plane-pairs x 111 float4 per plane (444 = 4*111)
    for (int i = threadIdx.x; i < 4 * 111; i += 256) {
      const int p = i / 111, i4 = i % 111;
      const float4 a  = *(const float4*)(xp + (2 * p) * H1S + 4 * i4);
      const float4 b4 = *(const float4*)(xp + (2 * p + 1) * H1S + 4 * i4);
#pragma unroll
      for (int j = 0; j < 4; j++) {
        const int e = 4 * i4 + j;
        if (e < 441) sxp[bb][p][e / 21][e % 21] = pkrtz((&a.x)[j], (&b4.x)[j]);
      }
    }
  }
  __syncthreads();
  const unsigned* wg = wf + (size_t)(g * 16) * 36;   // [oc][p][9], uniform
  const float* bg = bias + g * 16;                   // uniform
  for (int u = threadIdx.x; u < nbb * 81; u += 256) {
    const int bb = u / 81, pp = u % 81, py = pp / 9, px = pp % 9;
    const int iy = 2 * py, ix = 2 * px;
    float acc[16][4];
#pragma unroll
    for (int o = 0; o < 16; o++)
#pragma unroll
      for (int q = 0; q < 4; q++) acc[o][q] = 0.f;
#pragma unroll 1   // sequential ic-pair phases
    for (int p = 0; p < 4; p++) {
      unsigned winp[4][4];
#pragma unroll
      for (int r = 0; r < 4; r++)
#pragma unroll
        for (int c = 0; c < 4; c++) winp[r][c] = sxp[bb][p][iy + r][ix + c];
#pragma unroll
      for (int oc = 0; oc < 16; oc++) {
        const unsigned* wq = wg + (oc * 4 + p) * 9;   // uniform -> SGPR
#pragma unroll
        for (int ky = 0; ky < 3; ky++)
#pragma unroll
          for (int kx = 0; kx < 3; kx++) {
            const unsigned wv = wq[ky * 3 + kx];
            acc[oc][0] = dot2(winp[ky][kx],         wv, acc[oc][0]);
            acc[oc][1] = dot2(winp[ky][kx + 1],     wv, acc[oc][1]);
            acc[oc][2] = dot2(winp[ky + 1][kx],     wv, acc[oc][2]);
            acc[oc][3] = dot2(winp[ky + 1][kx + 1], wv, acc[oc][3]);
          }
      }
    }
#pragma unroll
    for (int oc = 0; oc < 16; oc++) {
      const float v = fmaxf(fmaxf(acc[oc][0], acc[oc][1]), fmaxf(acc[oc][2], acc[oc][3])) + bg[oc];
      out[(size_t)((b0 + bb) * 1152 + g * 16 + oc) * H2S + pp] = fmaxf(v, 0.f);
    }
  }
}

// ---------------- conv3: h2(stride 84) -> k3 (16->32) -> relu -> pool2 -> h3(9)
#define C3_NBB 7
__global__ __launch_bounds__(256) void conv3_k(const float* __restrict__ x,
                                               const unsigned* __restrict__ wf,
                                               const float* __restrict__ bias,
                                               float* __restrict__ out) {
  const int g = blockIdx.x % NG, b0 = (blockIdx.x / NG) * C3_NBB;
  const int nbb = min(C3_NBB, 64 - b0);
  __shared__ unsigned sxp[C3_NBB][8][9][10];   // half2 ic-pairs, pitch 10
  for (int bb = 0; bb < nbb; bb++) {
    const float* xp = x + (size_t)((b0 + bb) * 1152 + g * 16) * H2S;
    // float4 staging: 8 plane-pairs x 21 float4 per plane (84 = 4*21)
    for (int i = threadIdx.x; i < 8 * 21; i += 256) {
      const int p = i / 21, i4 = i % 21;
      const float4 a  = *(const float4*)(xp + (2 * p) * H2S + 4 * i4);
      const float4 b4 = *(const float4*)(xp + (2 * p + 1) * H2S + 4 * i4);
#pragma unroll
      for (int j = 0; j < 4; j++) {
        const int e = 4 * i4 + j;
        if (e < 81) sxp[bb][p][e / 9][e % 9] = pkrtz((&a.x)[j], (&b4.x)[j]);
      }
    }
  }
  __syncthreads();
  const int ocg = __builtin_amdgcn_readfirstlane(threadIdx.x >> 6);  // uniform
  const unsigned* wg = wf + ((size_t)(g * 32 + ocg * 8)) * 72;       // [oc][p][9]
  const float* bg = bias + g * 32 + ocg * 8;                         // uniform
  const int lane = threadIdx.x & 63;
  const int bb = lane / 9, pp = lane % 9;
  if (bb < nbb) {
    const int py = pp / 3, px = pp % 3, iy = 2 * py, ix = 2 * px;
    float acc[8][4];
#pragma unroll
    for (int o = 0; o < 8; o++)
#pragma unroll
      for (int q = 0; q < 4; q++) acc[o][q] = 0.f;
#pragma unroll 1
    for (int p = 0; p < 8; p++) {
      unsigned winp[4][4];
#pragma unroll
      for (int r = 0; r < 4; r++)
#pragma unroll
        for (int c = 0; c < 4; c++) winp[r][c] = sxp[bb][p][iy + r][ix + c];
#pragma unroll
      for (int o8 = 0; o8 < 8; o8++) {
        const unsigned* wq = wg + (o8 * 8 + p) * 9;   // uniform -> SGPR
#pragma unroll
        for (int ky = 0; ky < 3; ky++)
#pragma unroll
          for (int kx = 0; kx < 3; kx++) {
            const unsigned wv = wq[ky * 3 + kx];
            acc[o8][0] = dot2(winp[ky][kx],         wv, acc[o8][0]);
            acc[o8][1] = dot2(winp[ky][kx + 1],     wv, acc[o8][1]);
            acc[o8][2] = dot2(winp[ky + 1][kx],     wv, acc[o8][2]);
            acc[o8][3] = dot2(winp[ky + 1][kx + 1], wv, acc[o8][3]);
          }
      }
    }
#pragma unroll
    for (int o8 = 0; o8 < 8; o8++) {
      const float v = fmaxf(fmaxf(acc[o8][0], acc[o8][1]), fmaxf(acc[o8][2], acc[o8][3])) + bg[o8];
      out[(size_t)((b0 + bb) * 2304 + g * 32 + ocg * 8 + o8) * 9 + pp] = fmaxf(v, 0.f);
    }
  }
}

// ---------------- fused block-diagonal linear1 (288->64) + linear2 (64->2) + bias
__global__ __launch_bounds__(256) void lin_k(const float* __restrict__ h,
                                             const float* __restrict__ w1,
                                             const float* __restrict__ w2,
                                             const float* __restrict__ b2,
                                             float* __restrict__ out) {
  const int g = blockIdx.x % NG, b0 = (blockIdx.x / NG) * 32;
  __shared__ float sw1[64 * 292];
  __shared__ float sf[32 * 300];
  __shared__ float so[32 * 65];
  __shared__ float sw2[2 * 64];
  __shared__ float sb2[2];
  for (int i = threadIdx.x; i < 64 * 288; i += 256) {
    const int o = i / 288, k = i % 288;
    sw1[o * 292 + k] = w1[(size_t)(g * 64 + o) * 20736 + g * 288 + k];
  }
  for (int i = threadIdx.x; i < 32 * 288; i += 256) {
    const int bb = i / 288, k = i % 288;
    sf[bb * 300 + k] = h[(size_t)(b0 + bb) * 20736 + g * 288 + k];
  }
  if (threadIdx.x < 128) {
    const int j = threadIdx.x >> 6, o = threadIdx.x & 63;
    sw2[j * 64 + o] = w2[(size_t)(g * 2 + j) * 4608 + g * 64 + o];
  }
  if (threadIdx.x < 2) sb2[threadIdx.x] = b2[g * 2 + threadIdx.x];
  __syncthreads();
  const int bp = threadIdx.x & 15, oq = threadIdx.x >> 4;
  const int o0 = 4 * oq;
  float acc[2][4];
#pragma unroll
  for (int i = 0; i < 2; i++)
#pragma unroll
    for (int j = 0; j < 4; j++) acc[i][j] = 0.f;
  for (int k4 = 0; k4 < 72; k4++) {
    const float4 f0 = *(const float4*)&sf[bp * 300 + 4 * k4];
    const float4 f1 = *(const float4*)&sf[(bp + 16) * 300 + 4 * k4];
#pragma unroll
    for (int j = 0; j < 4; j++) {
      const float4 wr = *(const float4*)&sw1[(o0 + j) * 292 + 4 * k4];
      acc[0][j] = fmaf(f0.x, wr.x, fmaf(f0.y, wr.y, fmaf(f0.z, wr.z, fmaf(f0.w, wr.w, acc[0][j]))));
      acc[1][j] = fmaf(f1.x, wr.x, fmaf(f1.y, wr.y, fmaf(f1.z, wr.z, fmaf(f1.w, wr.w, acc[1][j]))));
    }
  }
#pragma unroll
  for (int j = 0; j < 4; j++) {
    so[bp * 65 + o0 + j] = acc[0][j];
    so[(bp + 16) * 65 + o0 + j] = acc[1][j];
  }
  __syncthreads();
  if (threadIdx.x < 64) {
    const int bb = threadIdx.x >> 1, j = threadIdx.x & 1;
    float a = sb2[j];
#pragma unroll 8
    for (int o = 0; o < 64; o++) a = fmaf(so[bb * 65 + o], sw2[j * 64 + o], a);
    out[(b0 + bb) * 144 + g * 2 + j] = a;
  }
}

extern "C" void kernel_launch(void* const* d_in, const int* in_sizes, int n_in,
                              void* d_out, int out_size, void* d_ws, size_t ws_size,
                              hipStream_t stream) {
  const float* x   = (const float*)d_in[0];
  const float* w1  = (const float*)d_in[1];
  const float* b1  = (const float*)d_in[2];
  const float* w2  = (const float*)d_in[3];
  const float* b2  = (const float*)d_in[4];
  const float* w3  = (const float*)d_in[5];
  const float* b3  = (const float*)d_in[6];
  const float* l1w = (const float*)d_in[7];
  const float* l2w = (const float*)d_in[8];
  const float* l2b = (const float*)d_in[9];
  float* out = (float*)d_out;

  float* h1 = (float*)d_ws;           // 64*576*444 = 16,367,616 floats (padded)
  float* h2 = h1 + 16367616;          // 64*1152*84 =  6,193,152 floats (padded)
  float* h3 = h2 + 6193152;           // 64*2304*9  =  1,327,104 floats (dense)
  unsigned* wf = (unsigned*)(h3 + 1327104);  // packed f16 weights (236160 u32)

  prep_k <<<dim3(923),     256, 0, stream>>>(w1, w2, w3, wf);
  conv1_k<<<dim3(64 * NG), 448, 0, stream>>>(x,  wf,         b1, h1);
  conv2_k<<<dim3(22 * NG), 256, 0, stream>>>(h1, wf + 28800, b2, h2);
  conv3_k<<<dim3(10 * NG), 256, 0, stream>>>(h2, wf + 70272, b3, h3);
  lin_k  <<<dim3(2 * NG),  256, 0, stream>>>(h3, l1w, l2w, l2b, out);
}